// Round 2
// baseline (798.928 us; speedup 1.0000x reference)
//
#include <hip/hip_runtime.h>
#include <hip/hip_bf16.h>

// LSTM cell fused: gates = [x,h] @ W + b ; i=sig(i); nc=(1-i)*c+i*tanh(j);
// nh=tanh(nc)*sig(o). B=16384, IN=H=1024, K=2048, 3H=3072.
// bf16 MFMA GEMM (128x64x3gates tile) + T2 both-sides XOR swizzle + fused epilogue.

#define B_DIM 16384
#define K_DIM 2048
#define H_DIM 1024

typedef __attribute__((ext_vector_type(8))) short short8;
typedef __attribute__((ext_vector_type(4))) short short4v;
typedef __attribute__((ext_vector_type(4))) float floatx4;

__device__ __forceinline__ short f2bf(float f) {
  unsigned u = __builtin_bit_cast(unsigned, f);
  u += 0x7fffu + ((u >> 16) & 1u);   // round-to-nearest-even
  return (short)(u >> 16);
}

__device__ __forceinline__ float sigm(float x) { return 1.f / (1.f + __expf(-x)); }
__device__ __forceinline__ float tanh_f(float x) {
  float e = __expf(2.f * x);
  return 1.f - 2.f / (e + 1.f);      // exact limits at +-inf
}

// ---------------- Kernel 1: concat(x,h) -> bf16 A [16384][2048] ----------------
// Dense 16B/lane loads: each thread converts 4 x-elems and 4 h-elems.
__global__ __launch_bounds__(256) void concat_cast_kernel(
    const float* __restrict__ x, const float* __restrict__ h, short* __restrict__ A) {
  long t = (long)blockIdx.x * 256 + threadIdx.x;
  long e = t * 4;                      // element index within x (and within h)
  int r = (int)(e >> 10);
  int k = (int)(e & 1023);
  floatx4 vx = *(const floatx4*)(x + e);
  floatx4 vh = *(const floatx4*)(h + e);
  short4v ox, oh;
  ox[0] = f2bf(vx[0]); ox[1] = f2bf(vx[1]); ox[2] = f2bf(vx[2]); ox[3] = f2bf(vx[3]);
  oh[0] = f2bf(vh[0]); oh[1] = f2bf(vh[1]); oh[2] = f2bf(vh[2]); oh[3] = f2bf(vh[3]);
  long base = (long)r * 2048 + k;
  *(short4v*)(A + base) = ox;
  *(short4v*)(A + base + 1024) = oh;
}

// ---------------- Kernel 2: W [2048][3072] f32 -> Wt [3072][2048] bf16 ----------------
__global__ __launch_bounds__(256) void wtrans_kernel(
    const float* __restrict__ W, short* __restrict__ Wt) {
  __shared__ float t[64][65];         // +1 pad: conflict-free column reads
  int tid = threadIdx.x;
  int kt = blockIdx.x * 64;           // k-tile base (2048/64 = 32)
  int nt = blockIdx.y * 64;           // n-tile base (3072/64 = 48)
  int rr = tid >> 4;                  // 0..15
  int c4 = (tid & 15) * 4;            // 0..60
#pragma unroll
  for (int it = 0; it < 4; ++it) {
    int row = it * 16 + rr;
    floatx4 v = *(const floatx4*)&W[(long)(kt + row) * 3072 + nt + c4];
    t[row][c4 + 0] = v[0]; t[row][c4 + 1] = v[1];
    t[row][c4 + 2] = v[2]; t[row][c4 + 3] = v[3];
  }
  __syncthreads();
#pragma unroll
  for (int it = 0; it < 4; ++it) {
    int n_ = it * 16 + rr;
    short4v s;
    s[0] = f2bf(t[c4 + 0][n_]); s[1] = f2bf(t[c4 + 1][n_]);
    s[2] = f2bf(t[c4 + 2][n_]); s[3] = f2bf(t[c4 + 3][n_]);
    *(short4v*)&Wt[(long)(nt + n_) * 2048 + kt + c4] = s;
  }
}

// ---------------- Kernel 3: fused GEMM + LSTM epilogue ----------------
// Tile: BM=128 rows x BN=64 cols x 3 gates. BK=64. 256 threads (4 waves).
// LDS rows are 128B (64 bf16): T2 XOR swizzle chunk ^= (row&7), both sides.
#define BM 128
#define BN 64
#define BK 64

__device__ __forceinline__ void gload_lds16(const void* g, void* l) {
  __builtin_amdgcn_global_load_lds(
      (const __attribute__((address_space(1))) void*)g,
      (__attribute__((address_space(3))) void*)l, 16, 0, 0);
}

__global__ __launch_bounds__(256, 4) void lstm_gemm_kernel(
    const short* __restrict__ A, const short* __restrict__ Wt,
    const float* __restrict__ bias, const float* __restrict__ Cin,
    float* __restrict__ out) {
  __shared__ short As[BM * BK];        // 16 KB
  __shared__ short Ws[3][BN * BK];     // 24 KB  (total 40 KB -> 4 blocks/CU)
  const int tid = threadIdx.x;
  const int lane = tid & 63;
  const int wave = tid >> 6;
  const int m0 = blockIdx.x * BM;
  const int n0 = blockIdx.y * BN;
  const int lr = lane & 15;            // fragment row/col index
  const int lg = lane >> 4;            // k-group 0..3
  const int srow = tid >> 3;           // staging row 0..31
  const int sch = tid & 7;             // staging chunk 0..7 (16B units)

  floatx4 acc[3][2][4] = {};

  for (int k0 = 0; k0 < K_DIM; k0 += BK) {
    // stage A tile (128 rows x 64 bf16): linear LDS dest, inverse-swizzled source
#pragma unroll
    for (int it = 0; it < 4; ++it) {
      int r = it * 32 + srow;
      int chs = sch ^ (r & 7);         // logical chunk that belongs at physical slot sch
      gload_lds16(A + (long)(m0 + r) * K_DIM + k0 + chs * 8, As + r * BK + sch * 8);
    }
    // stage 3 W tiles (64 rows x 64 bf16 each)
#pragma unroll
    for (int g = 0; g < 3; ++g) {
#pragma unroll
      for (int it = 0; it < 2; ++it) {
        int r = it * 32 + srow;
        int chs = sch ^ (r & 7);
        gload_lds16(Wt + (long)(g * 1024 + n0 + r) * K_DIM + k0 + chs * 8,
                    Ws[g] + r * BK + sch * 8);
      }
    }
    __syncthreads();   // compiler drains vmcnt before barrier

#pragma unroll
    for (int kk = 0; kk < BK; kk += 32) {
      short8 af[2];
#pragma unroll
      for (int mr = 0; mr < 2; ++mr) {
        int row = wave * 32 + mr * 16 + lr;
        af[mr] = *(const short8*)&As[row * BK + ((((kk >> 3) + lg) ^ (row & 7)) << 3)];
      }
#pragma unroll
      for (int g = 0; g < 3; ++g) {
#pragma unroll
        for (int nr = 0; nr < 4; ++nr) {
          int rowb = nr * 16 + lr;
          short8 bf = *(const short8*)
              &Ws[g][rowb * BK + ((((kk >> 3) + lg) ^ (rowb & 7)) << 3)];
#pragma unroll
          for (int mr = 0; mr < 2; ++mr)
            acc[g][mr][nr] = __builtin_amdgcn_mfma_f32_16x16x32_bf16(
                af[mr], bf, acc[g][mr][nr], 0, 0, 0);
        }
      }
    }
    __syncthreads();
  }

  // Epilogue: D mapping row=(lane>>4)*4+reg, col=lane&15 (m89-verified)
  const float* bi = bias;
  const float* bj = bias + 1024;
  const float* bo = bias + 2048;
#pragma unroll
  for (int mr = 0; mr < 2; ++mr) {
#pragma unroll
    for (int nr = 0; nr < 4; ++nr) {
      int col = n0 + nr * 16 + lr;
      float vbi = bi[col], vbj = bj[col], vbo = bo[col];
#pragma unroll
      for (int r = 0; r < 4; ++r) {
        int row = m0 + wave * 32 + mr * 16 + lg * 4 + r;
        float xi = acc[0][mr][nr][r] + vbi;
        float xj = acc[1][mr][nr][r] + vbj;
        float xo = acc[2][mr][nr][r] + vbo;
        float ii = sigm(xi);
        float tj = tanh_f(xj);
        float oc = Cin[(long)row * H_DIM + col];
        float nc = (1.f - ii) * oc + ii * tj;
        float nh = tanh_f(nc) * sigm(xo);
        long oidx = (long)row * H_DIM + col;
        out[oidx] = nh;
        out[(long)B_DIM * H_DIM + oidx] = nc;
      }
    }
  }
}

// ---------------- Fallback (ws too small): naive fp32, correctness-only ----------------
__global__ __launch_bounds__(256) void lstm_naive_kernel(
    const float* __restrict__ x, const float* __restrict__ h,
    const float* __restrict__ c, const float* __restrict__ W,
    const float* __restrict__ b, float* __restrict__ out) {
  long idx = (long)blockIdx.x * 256 + threadIdx.x;
  if (idx >= (long)B_DIM * H_DIM) return;
  int row = (int)(idx >> 10), col = (int)(idx & 1023);
  float si = b[col], sj = b[1024 + col], so = b[2048 + col];
  const float* xr = x + (long)row * 1024;
  const float* hr = h + (long)row * 1024;
  for (int k = 0; k < 1024; ++k) {
    float a = xr[k];
    const float* wr = W + (long)k * 3072 + col;
    si += a * wr[0]; sj += a * wr[1024]; so += a * wr[2048];
  }
  for (int k = 0; k < 1024; ++k) {
    float a = hr[k];
    const float* wr = W + (long)(1024 + k) * 3072 + col;
    si += a * wr[0]; sj += a * wr[1024]; so += a * wr[2048];
  }
  float ii = sigm(si);
  float tj = tanh_f(sj);
  float oc = c[idx];
  float nc = (1.f - ii) * oc + ii * tj;
  out[idx] = tanh_f(nc) * sigm(so);
  out[(long)B_DIM * H_DIM + idx] = nc;
}

extern "C" void kernel_launch(void* const* d_in, const int* in_sizes, int n_in,
                              void* d_out, int out_size, void* d_ws, size_t ws_size,
                              hipStream_t stream) {
  const float* x = (const float*)d_in[0];
  const float* h = (const float*)d_in[1];
  const float* c = (const float*)d_in[2];
  const float* W = (const float*)d_in[3];
  const float* b = (const float*)d_in[4];
  float* out = (float*)d_out;

  const size_t A_elems = (size_t)B_DIM * K_DIM;       // 33,554,432
  const size_t Wt_elems = (size_t)3072 * K_DIM;       //  6,291,456
  const size_t needed = (A_elems + Wt_elems) * 2;     // ~76 MiB

  if (ws_size < needed) {
    lstm_naive_kernel<<<(B_DIM * H_DIM) / 256, 256, 0, stream>>>(x, h, c, W, b, out);
    return;
  }

  short* Abf = (short*)d_ws;
  short* Wtb = Abf + A_elems;

  concat_cast_kernel<<<(B_DIM * 1024) / (256 * 4), 256, 0, stream>>>(x, h, Abf);
  wtrans_kernel<<<dim3(32, 48), 256, 0, stream>>>(W, Wtb);
  lstm_gemm_kernel<<<dim3(B_DIM / BM, H_DIM / BN), 256, 0, stream>>>(Abf, Wtb, b, c, out);
}

// Round 3
// 482.948 us; speedup vs baseline: 1.6543x; 1.6543x over previous
//
#include <hip/hip_runtime.h>
#include <hip/hip_bf16.h>

// LSTM cell fused: gates = [x,h] @ W + b ; i=sig(i); nc=(1-i)*c+i*tanh(j);
// nh=tanh(nc)*sig(o). B=16384, IN=H=1024, K=2048, 3H=3072.
// bf16 MFMA GEMM (128x64x3gates tile, 2x2 waves, mr=4) + T2 XOR swizzle + fused epilogue.
// launch_bounds(256,2): (256,4) capped regs at 128/wave -> 96-reg accumulator SPILLED
// (WRITE_SIZE 1.2GB scratch traffic, round-2 regression). Do not raise.

#define B_DIM 16384
#define K_DIM 2048
#define H_DIM 1024

typedef __attribute__((ext_vector_type(8))) short short8;
typedef __attribute__((ext_vector_type(4))) short short4v;
typedef __attribute__((ext_vector_type(4))) float floatx4;

__device__ __forceinline__ short f2bf(float f) {
  unsigned u = __builtin_bit_cast(unsigned, f);
  u += 0x7fffu + ((u >> 16) & 1u);   // round-to-nearest-even
  return (short)(u >> 16);
}

__device__ __forceinline__ float sigm(float x) { return 1.f / (1.f + __expf(-x)); }
__device__ __forceinline__ float tanh_f(float x) {
  float e = __expf(2.f * x);
  return 1.f - 2.f / (e + 1.f);      // exact limits at +-inf
}

// ---------------- Kernel 1 (fused prep): concat-cast + W transpose-cast ----------------
// Blocks [0, 16384): concat(x,h) -> bf16 A [16384][2048]
// Blocks [16384, 17920): W [2048][3072] f32 -> Wt [3072][2048] bf16
#define CONCAT_BLOCKS 16384

__global__ __launch_bounds__(256) void prep_kernel(
    const float* __restrict__ x, const float* __restrict__ h,
    const float* __restrict__ W, short* __restrict__ A, short* __restrict__ Wt) {
  __shared__ float t[64][65];          // wtrans only; +1 pad for column reads
  int tid = threadIdx.x;
  if (blockIdx.x < CONCAT_BLOCKS) {
    long tt = (long)blockIdx.x * 256 + tid;
    long e = tt * 4;                   // element index within x (and within h)
    int r = (int)(e >> 10);
    int k = (int)(e & 1023);
    floatx4 vx = *(const floatx4*)(x + e);
    floatx4 vh = *(const floatx4*)(h + e);
    short4v ox, oh;
    ox[0] = f2bf(vx[0]); ox[1] = f2bf(vx[1]); ox[2] = f2bf(vx[2]); ox[3] = f2bf(vx[3]);
    oh[0] = f2bf(vh[0]); oh[1] = f2bf(vh[1]); oh[2] = f2bf(vh[2]); oh[3] = f2bf(vh[3]);
    long base = (long)r * 2048 + k;
    *(short4v*)(A + base) = ox;
    *(short4v*)(A + base + 1024) = oh;
  } else {
    int bid = blockIdx.x - CONCAT_BLOCKS;
    int kt = (bid & 31) << 6;          // k-tile base (2048/64 = 32)
    int nt = (bid >> 5) << 6;          // n-tile base (3072/64 = 48)
    int rr = tid >> 4;                 // 0..15
    int c4 = (tid & 15) * 4;           // 0..60
#pragma unroll
    for (int it = 0; it < 4; ++it) {
      int row = it * 16 + rr;
      floatx4 v = *(const floatx4*)&W[(long)(kt + row) * 3072 + nt + c4];
      t[row][c4 + 0] = v[0]; t[row][c4 + 1] = v[1];
      t[row][c4 + 2] = v[2]; t[row][c4 + 3] = v[3];
    }
    __syncthreads();
#pragma unroll
    for (int it = 0; it < 4; ++it) {
      int n_ = it * 16 + rr;
      short4v s;
      s[0] = f2bf(t[c4 + 0][n_]); s[1] = f2bf(t[c4 + 1][n_]);
      s[2] = f2bf(t[c4 + 2][n_]); s[3] = f2bf(t[c4 + 3][n_]);
      *(short4v*)&Wt[(long)(nt + n_) * 2048 + kt + c4] = s;
    }
  }
}

// ---------------- Kernel 2: fused GEMM + LSTM epilogue ----------------
// Tile: BM=128 x BN=64 x 3 gates. BK=64. 256 threads = 4 waves arranged 2Mx2N.
// Wave tile: 64 rows (mr=4) x 32 cols (nr=2) x 3 gates -> acc 96 VGPRs.
// Per kk: 4 A-frag + 6 B-frag ds_read_b128 (~240cy) vs 24 MFMA (~240cy) - balanced.
// LDS rows 128B: T2 XOR swizzle chunk ^= (row&7), both-sides (rule #21).
#define BM 128
#define BN 64
#define BK 64

__device__ __forceinline__ void gload_lds16(const void* g, void* l) {
  __builtin_amdgcn_global_load_lds(
      (const __attribute__((address_space(1))) void*)g,
      (__attribute__((address_space(3))) void*)l, 16, 0, 0);
}

__global__ __launch_bounds__(256, 2) void lstm_gemm_kernel(
    const short* __restrict__ A, const short* __restrict__ Wt,
    const float* __restrict__ bias, const float* __restrict__ Cin,
    float* __restrict__ out) {
  __shared__ short As[BM * BK];        // 16 KB
  __shared__ short Ws[3][BN * BK];     // 24 KB  (total 40 KB)
  const int tid = threadIdx.x;
  const int lane = tid & 63;
  const int wave = tid >> 6;
  const int wr = wave >> 1;            // wave row 0..1 (64-row strips)
  const int wc = wave & 1;             // wave col 0..1 (32-col strips)
  const int m0 = blockIdx.x * BM;
  const int n0 = blockIdx.y * BN;
  const int lr = lane & 15;            // fragment row/col index
  const int lg = lane >> 4;            // k-group 0..3
  const int srow = tid >> 3;           // staging row 0..31
  const int sch = tid & 7;             // staging chunk 0..7 (16B units)

  floatx4 acc[3][4][2] = {};

  for (int k0 = 0; k0 < K_DIM; k0 += BK) {
    // stage A tile (128 rows x 64 bf16): linear LDS dest, inverse-swizzled source
#pragma unroll
    for (int it = 0; it < 4; ++it) {
      int r = it * 32 + srow;
      int chs = sch ^ (r & 7);         // logical chunk for physical slot sch
      gload_lds16(A + (long)(m0 + r) * K_DIM + k0 + chs * 8, As + r * BK + sch * 8);
    }
    // stage 3 W tiles (64 rows x 64 bf16 each)
#pragma unroll
    for (int g = 0; g < 3; ++g) {
#pragma unroll
      for (int it = 0; it < 2; ++it) {
        int r = it * 32 + srow;
        int chs = sch ^ (r & 7);
        gload_lds16(Wt + (long)(g * 1024 + n0 + r) * K_DIM + k0 + chs * 8,
                    Ws[g] + r * BK + sch * 8);
      }
    }
    __syncthreads();   // compiler drains vmcnt before barrier

#pragma unroll
    for (int kk = 0; kk < BK; kk += 32) {
      short8 af[4];
#pragma unroll
      for (int mr = 0; mr < 4; ++mr) {
        int row = wr * 64 + mr * 16 + lr;
        af[mr] = *(const short8*)&As[row * BK + ((((kk >> 3) + lg) ^ (row & 7)) << 3)];
      }
#pragma unroll
      for (int g = 0; g < 3; ++g) {
#pragma unroll
        for (int nr = 0; nr < 2; ++nr) {
          int rowb = wc * 32 + nr * 16 + lr;
          short8 bf = *(const short8*)
              &Ws[g][rowb * BK + ((((kk >> 3) + lg) ^ (rowb & 7)) << 3)];
#pragma unroll
          for (int mr = 0; mr < 4; ++mr)
            acc[g][mr][nr] = __builtin_amdgcn_mfma_f32_16x16x32_bf16(
                af[mr], bf, acc[g][mr][nr], 0, 0, 0);
        }
      }
    }
    __syncthreads();
  }

  // Epilogue: D mapping row=(lane>>4)*4+reg, col=lane&15 (m89-verified)
  const float* bi = bias;
  const float* bj = bias + 1024;
  const float* bo = bias + 2048;
#pragma unroll
  for (int mr = 0; mr < 4; ++mr) {
#pragma unroll
    for (int nr = 0; nr < 2; ++nr) {
      int col = n0 + wc * 32 + nr * 16 + lr;
      float vbi = bi[col], vbj = bj[col], vbo = bo[col];
#pragma unroll
      for (int r = 0; r < 4; ++r) {
        int row = m0 + wr * 64 + mr * 16 + lg * 4 + r;
        float xi = acc[0][mr][nr][r] + vbi;
        float xj = acc[1][mr][nr][r] + vbj;
        float xo = acc[2][mr][nr][r] + vbo;
        float ii = sigm(xi);
        float tj = tanh_f(xj);
        float oc = Cin[(long)row * H_DIM + col];
        float nc = (1.f - ii) * oc + ii * tj;
        float nh = tanh_f(nc) * sigm(xo);
        long oidx = (long)row * H_DIM + col;
        out[oidx] = nh;
        out[(long)B_DIM * H_DIM + oidx] = nc;
      }
    }
  }
}

// ---------------- Fallback (ws too small): naive fp32, correctness-only ----------------
__global__ __launch_bounds__(256) void lstm_naive_kernel(
    const float* __restrict__ x, const float* __restrict__ h,
    const float* __restrict__ c, const float* __restrict__ W,
    const float* __restrict__ b, float* __restrict__ out) {
  long idx = (long)blockIdx.x * 256 + threadIdx.x;
  if (idx >= (long)B_DIM * H_DIM) return;
  int row = (int)(idx >> 10), col = (int)(idx & 1023);
  float si = b[col], sj = b[1024 + col], so = b[2048 + col];
  const float* xr = x + (long)row * 1024;
  const float* hr = h + (long)row * 1024;
  for (int k = 0; k < 1024; ++k) {
    float a = xr[k];
    const float* wr = W + (long)k * 3072 + col;
    si += a * wr[0]; sj += a * wr[1024]; so += a * wr[2048];
  }
  for (int k = 0; k < 1024; ++k) {
    float a = hr[k];
    const float* wr = W + (long)(1024 + k) * 3072 + col;
    si += a * wr[0]; sj += a * wr[1024]; so += a * wr[2048];
  }
  float ii = sigm(si);
  float tj = tanh_f(sj);
  float oc = c[idx];
  float nc = (1.f - ii) * oc + ii * tj;
  out[idx] = tanh_f(nc) * sigm(so);
  out[(long)B_DIM * H_DIM + idx] = nc;
}

extern "C" void kernel_launch(void* const* d_in, const int* in_sizes, int n_in,
                              void* d_out, int out_size, void* d_ws, size_t ws_size,
                              hipStream_t stream) {
  const float* x = (const float*)d_in[0];
  const float* h = (const float*)d_in[1];
  const float* c = (const float*)d_in[2];
  const float* W = (const float*)d_in[3];
  const float* b = (const float*)d_in[4];
  float* out = (float*)d_out;

  const size_t A_elems = (size_t)B_DIM * K_DIM;       // 33,554,432
  const size_t Wt_elems = (size_t)3072 * K_DIM;       //  6,291,456
  const size_t needed = (A_elems + Wt_elems) * 2;     // ~76 MiB

  if (ws_size < needed) {
    lstm_naive_kernel<<<(B_DIM * H_DIM) / 256, 256, 0, stream>>>(x, h, c, W, b, out);
    return;
  }

  short* Abf = (short*)d_ws;
  short* Wtb = Abf + A_elems;

  prep_kernel<<<CONCAT_BLOCKS + 32 * 48, 256, 0, stream>>>(x, h, W, Abf, Wtb);
  lstm_gemm_kernel<<<dim3(B_DIM / BM, H_DIM / BN), 256, 0, stream>>>(Abf, Wtb, b, c, out);
}